// Round 1
// baseline (1153.582 us; speedup 1.0000x reference)
//
#include <hip/hip_runtime.h>

#define BB 32
#define NN 512
#define EE 256
#define HH 8
#define HDD 32
#define MM (BB*NN)   // 16384

// ---------------- Kernel 1: QKV projection ----------------
// qkv[m][j] = sum_k x[m][k] * in_w[j][k] + in_b[j], scattered to head-major Q/K/V
__global__ __launch_bounds__(256) void qkv_kernel(
    const float* __restrict__ x, const float* __restrict__ w,
    const float* __restrict__ bias,
    float* __restrict__ Q, float* __restrict__ K, float* __restrict__ V) {
  __shared__ float As[16][68];
  __shared__ float Bs[16][68];
  int t = threadIdx.x;
  int bx = blockIdx.x % 12;   // col tile (64 cols of 768)
  int by = blockIdx.x / 12;   // row tile (64 rows of 16384)
  int m0 = by * 64, j0 = bx * 64;
  int tx = t & 15, ty = t >> 4;
  float4 c4[4];
  #pragma unroll
  for (int i = 0; i < 4; i++) { c4[i].x = 0.f; c4[i].y = 0.f; c4[i].z = 0.f; c4[i].w = 0.f; }
  int skk = t & 15, sbase = t >> 4;
  for (int kc = 0; kc < 256; kc += 16) {
    __syncthreads();
    #pragma unroll
    for (int i = 0; i < 4; i++) {
      int mm = sbase + 16 * i;
      As[skk][mm] = x[(m0 + mm) * 256 + kc + skk];
      Bs[skk][mm] = w[(j0 + mm) * 256 + kc + skk];
    }
    __syncthreads();
    #pragma unroll
    for (int k2 = 0; k2 < 16; k2++) {
      float4 bv = *(const float4*)&Bs[k2][tx * 4];
      #pragma unroll
      for (int i = 0; i < 4; i++) {
        float a = As[k2][ty * 4 + i];
        c4[i].x += a * bv.x; c4[i].y += a * bv.y; c4[i].z += a * bv.z; c4[i].w += a * bv.w;
      }
    }
  }
  int j = j0 + tx * 4;
  int which = j >> 8;           // 0=q 1=k 2=v
  int e0 = j & 255;
  int h = e0 >> 5, d0 = e0 & 31;
  float* dst = (which == 0) ? Q : ((which == 1) ? K : V);
  float4 b4 = *(const float4*)&bias[j];
  #pragma unroll
  for (int i = 0; i < 4; i++) {
    int m = m0 + ty * 4 + i;
    int bi = m >> 9, n = m & 511;
    float4 v;
    v.x = c4[i].x + b4.x; v.y = c4[i].y + b4.y; v.z = c4[i].z + b4.z; v.w = c4[i].w + b4.w;
    *(float4*)&dst[(((bi * 8 + h) * 512 + n) * 32) + d0] = v;
  }
}

// ---------------- Kernel 2: attention, all heads per (b, 16-q tile) ----------------
__global__ __launch_bounds__(256) void attn_kernel(
    const float* __restrict__ Q, const float* __restrict__ K,
    const float* __restrict__ V, const int* __restrict__ pre_mask,
    float* __restrict__ o, float* __restrict__ attnw) {
  __shared__ float sS[16][520];
  __shared__ float sKV[128][36];
  __shared__ float sQ[16][36];
  __shared__ float red[16][17];
  int t = threadIdx.x;
  int bb = blockIdx.x >> 5;
  int q0 = (blockIdx.x & 31) << 4;
  const float scale = 0.17677669529663687f;  // 1/sqrt(32)
  // ownerships
  int sqi = t >> 4, skl = t & 15;            // softmax / wmean: row sqi, cols skl+16j
  int sgq = t >> 6, sgk = t & 63;            // scores: q rows sgq*4+i, k = sgk, sgk+64
  int pkq = t >> 6;                           // PV k-quarter
  int pr = t & 63;
  int pqg = pr >> 4, pdl = pr & 15;          // PV: q rows pqg*4+i, d = pdl, pdl+16
  float wmean[32];
  #pragma unroll
  for (int j = 0; j < 32; j++) wmean[j] = 0.f;

  for (int h = 0; h < 8; h++) {
    int base = (bb * 8 + h) * 16384;   // *512*32
    __syncthreads();
    if (t < 128) {
      int row = t >> 3, d0 = (t & 7) * 4;
      *(float4*)&sQ[row][d0] = *(const float4*)&Q[base + (q0 + row) * 32 + d0];
    }
    // ---- scores ----
    for (int c = 0; c < 4; c++) {
      __syncthreads();
      #pragma unroll
      for (int i = 0; i < 4; i++) {
        int idx = t + i * 256;
        int row = idx >> 3, d0 = (idx & 7) * 4;
        *(float4*)&sKV[row][d0] = *(const float4*)&K[base + (c * 128 + row) * 32 + d0];
      }
      __syncthreads();
      float acc[4][2];
      #pragma unroll
      for (int i = 0; i < 4; i++) { acc[i][0] = 0.f; acc[i][1] = 0.f; }
      #pragma unroll
      for (int d4 = 0; d4 < 8; d4++) {
        float4 k0 = *(const float4*)&sKV[sgk][d4 * 4];
        float4 k1 = *(const float4*)&sKV[sgk + 64][d4 * 4];
        #pragma unroll
        for (int i = 0; i < 4; i++) {
          float4 qv = *(const float4*)&sQ[sgq * 4 + i][d4 * 4];
          acc[i][0] += qv.x * k0.x + qv.y * k0.y + qv.z * k0.z + qv.w * k0.w;
          acc[i][1] += qv.x * k1.x + qv.y * k1.y + qv.z * k1.z + qv.w * k1.w;
        }
      }
      const int* mrow = pre_mask + ((bb * 8 + h) * 512 + q0) * 512;
      #pragma unroll
      for (int i = 0; i < 4; i++) {
        int qr = sgq * 4 + i;
        int kA = c * 128 + sgk, kB = kA + 64;
        int mA = mrow[qr * 512 + kA];
        int mB = mrow[qr * 512 + kB];
        sS[qr][kA] = mA ? -1e9f : acc[i][0] * scale;
        sS[qr][kB] = mB ? -1e9f : acc[i][1] * scale;
      }
    }
    __syncthreads();
    // ---- softmax over row sqi ----
    float mx = -3e38f;
    #pragma unroll
    for (int j = 0; j < 32; j++) mx = fmaxf(mx, sS[sqi][skl + 16 * j]);
    red[sqi][skl] = mx;
    __syncthreads();
    if (skl == 0) {
      float m2 = red[sqi][0];
      for (int j2 = 1; j2 < 16; j2++) m2 = fmaxf(m2, red[sqi][j2]);
      red[sqi][16] = m2;
    }
    __syncthreads();
    float rowm = red[sqi][16];
    float ev[32];
    float sum = 0.f;
    #pragma unroll
    for (int j = 0; j < 32; j++) {
      float e = __expf(sS[sqi][skl + 16 * j] - rowm);
      ev[j] = e; sum += e;
    }
    __syncthreads();
    red[sqi][skl] = sum;
    __syncthreads();
    if (skl == 0) {
      float s2 = 0.f;
      for (int j2 = 0; j2 < 16; j2++) s2 += red[sqi][j2];
      red[sqi][16] = s2;
    }
    __syncthreads();
    float inv = 1.0f / red[sqi][16];
    #pragma unroll
    for (int j = 0; j < 32; j++) {
      float wv = ev[j] * inv;
      sS[sqi][skl + 16 * j] = wv;
      wmean[j] += 0.125f * wv;
    }
    __syncthreads();
    // ---- PV ----
    float oacc[4][2];
    #pragma unroll
    for (int i = 0; i < 4; i++) { oacc[i][0] = 0.f; oacc[i][1] = 0.f; }
    for (int c = 0; c < 4; c++) {
      __syncthreads();
      #pragma unroll
      for (int i = 0; i < 4; i++) {
        int idx = t + i * 256;
        int row = idx >> 3, d0 = (idx & 7) * 4;
        *(float4*)&sKV[row][d0] = *(const float4*)&V[base + (c * 128 + row) * 32 + d0];
      }
      __syncthreads();
      #pragma unroll
      for (int k2 = 0; k2 < 32; k2++) {
        int kk = pkq * 32 + k2;
        float v0 = sKV[kk][pdl], v1 = sKV[kk][pdl + 16];
        int kg = c * 128 + kk;
        #pragma unroll
        for (int i = 0; i < 4; i++) {
          float wv = sS[pqg * 4 + i][kg];
          oacc[i][0] += wv * v0; oacc[i][1] += wv * v1;
        }
      }
    }
    // reduce the 4 k-quarters through LDS (reuse sKV)
    __syncthreads();
    float* rbuf = &sKV[0][0];
    if (pkq > 0) {
      #pragma unroll
      for (int i = 0; i < 4; i++) {
        rbuf[((pkq - 1) * 16 + pqg * 4 + i) * 32 + pdl] = oacc[i][0];
        rbuf[((pkq - 1) * 16 + pqg * 4 + i) * 32 + pdl + 16] = oacc[i][1];
      }
    }
    __syncthreads();
    if (pkq == 0) {
      #pragma unroll
      for (int i = 0; i < 4; i++) {
        int qr = pqg * 4 + i;
        float s0 = oacc[i][0], s1 = oacc[i][1];
        #pragma unroll
        for (int kq = 0; kq < 3; kq++) {
          s0 += rbuf[(kq * 16 + qr) * 32 + pdl];
          s1 += rbuf[(kq * 16 + qr) * 32 + pdl + 16];
        }
        o[(bb * 512 + q0 + qr) * 256 + h * 32 + pdl] = s0;
        o[(bb * 512 + q0 + qr) * 256 + h * 32 + pdl + 16] = s1;
      }
    }
  }
  // ---- head-averaged attention weights ----
  float* arow = attnw + (bb * 512 + q0 + sqi) * 512;
  #pragma unroll
  for (int j = 0; j < 32; j++) arow[skl + 16 * j] = wmean[j];
}

// ---------------- Kernel 3: out-proj + post-mask + residual + LayerNorm ----------------
__global__ __launch_bounds__(256) void proj_ln_kernel(
    const float* __restrict__ x, const float* __restrict__ w,
    const float* __restrict__ bias, const int* __restrict__ post_mask,
    const float* __restrict__ gamma, const float* __restrict__ beta,
    float* __restrict__ io /* o in, final out, in place */) {
  __shared__ float As[16][17];
  __shared__ float Bs[16][260];
  int t = threadIdx.x;
  int m0 = blockIdx.x * 16;
  int tx = t & 63, ty = t >> 6;
  float4 c4[4];
  #pragma unroll
  for (int i = 0; i < 4; i++) { c4[i].x = 0.f; c4[i].y = 0.f; c4[i].z = 0.f; c4[i].w = 0.f; }
  int skk = t & 15, srr = t >> 4;
  for (int kc = 0; kc < 256; kc += 16) {
    __syncthreads();
    As[skk][srr] = io[(m0 + srr) * 256 + kc + skk];
    #pragma unroll
    for (int i = 0; i < 16; i++) {
      int idx = t + i * 256;
      int kk = idx & 15, jj = idx >> 4;
      Bs[kk][jj] = w[jj * 256 + kc + kk];
    }
    __syncthreads();
    #pragma unroll
    for (int k2 = 0; k2 < 16; k2++) {
      float4 bv = *(const float4*)&Bs[k2][tx * 4];
      #pragma unroll
      for (int i = 0; i < 4; i++) {
        float a = As[k2][ty * 4 + i];
        c4[i].x += a * bv.x; c4[i].y += a * bv.y; c4[i].z += a * bv.z; c4[i].w += a * bv.w;
      }
    }
  }
  int j0 = tx * 4;
  float4 gm = *(const float4*)&gamma[j0];
  float4 bt = *(const float4*)&beta[j0];
  float4 ob = *(const float4*)&bias[j0];
  float4 yv[4];
  float s1[4], s2[4];
  #pragma unroll
  for (int i = 0; i < 4; i++) {
    int m = m0 + ty * 4 + i;
    int bi = m >> 9, n = m & 511;
    bool msk = post_mask[bi * 512 + n] != 0;
    float4 xv = *(const float4*)&x[m * 256 + j0];
    float4 pv;
    pv.x = msk ? 0.f : c4[i].x + ob.x;
    pv.y = msk ? 0.f : c4[i].y + ob.y;
    pv.z = msk ? 0.f : c4[i].z + ob.z;
    pv.w = msk ? 0.f : c4[i].w + ob.w;
    float4 y;
    y.x = xv.x + pv.x; y.y = xv.y + pv.y; y.z = xv.z + pv.z; y.w = xv.w + pv.w;
    yv[i] = y;
    s1[i] = y.x + y.y + y.z + y.w;
    s2[i] = y.x * y.x + y.y * y.y + y.z * y.z + y.w * y.w;
  }
  #pragma unroll
  for (int off = 32; off > 0; off >>= 1) {
    #pragma unroll
    for (int i = 0; i < 4; i++) {
      s1[i] += __shfl_xor(s1[i], off, 64);
      s2[i] += __shfl_xor(s2[i], off, 64);
    }
  }
  #pragma unroll
  for (int i = 0; i < 4; i++) {
    int m = m0 + ty * 4 + i;
    float mu = s1[i] * (1.0f / 256.0f);
    float var = s2[i] * (1.0f / 256.0f) - mu * mu;
    float rstd = rsqrtf(var + 1e-5f);
    float4 y = yv[i];
    float4 outv;
    outv.x = (y.x - mu) * rstd * gm.x + bt.x;
    outv.y = (y.y - mu) * rstd * gm.y + bt.y;
    outv.z = (y.z - mu) * rstd * gm.z + bt.z;
    outv.w = (y.w - mu) * rstd * gm.w + bt.w;
    *(float4*)&io[m * 256 + j0] = outv;
  }
}

extern "C" void kernel_launch(void* const* d_in, const int* in_sizes, int n_in,
                              void* d_out, int out_size, void* d_ws, size_t ws_size,
                              hipStream_t stream) {
  const float* x       = (const float*)d_in[0];
  const int*   pre_m   = (const int*)d_in[1];
  const int*   post_m  = (const int*)d_in[2];
  const float* in_w    = (const float*)d_in[3];
  const float* in_b    = (const float*)d_in[4];
  const float* out_w   = (const float*)d_in[5];
  const float* out_b   = (const float*)d_in[6];
  const float* gamma   = (const float*)d_in[7];
  const float* beta    = (const float*)d_in[8];
  float* out   = (float*)d_out;                       // [B,N,E]
  float* attnw = out + (size_t)BB * NN * EE;          // [B,N,N]
  float* Q = (float*)d_ws;                            // [B,H,N,32] each
  float* K = Q + (size_t)BB * HH * NN * HDD;
  float* V = K + (size_t)BB * HH * NN * HDD;

  qkv_kernel<<<dim3(3072), dim3(256), 0, stream>>>(x, in_w, in_b, Q, K, V);
  attn_kernel<<<dim3(1024), dim3(256), 0, stream>>>(Q, K, V, pre_m, out, attnw);
  proj_ln_kernel<<<dim3(1024), dim3(256), 0, stream>>>(x, out_w, out_b, post_m, gamma, beta, out);
}

// Round 2
// 544.174 us; speedup vs baseline: 2.1199x; 2.1199x over previous
//
#include <hip/hip_runtime.h>

#define BB 32
#define NN 512
#define EE 256
#define HH 8
#define HDD 32

typedef __attribute__((ext_vector_type(4))) float f32x4;
typedef __attribute__((ext_vector_type(8))) short s16x8;
typedef unsigned short ushort_t;
typedef unsigned int uint_t;

__device__ __forceinline__ ushort_t f2bf(float f) {
  union { float f; uint_t u; } v; v.f = f;
  uint_t r = v.u + 0x7fffu + ((v.u >> 16) & 1u);
  return (ushort_t)(r >> 16);
}

// ---------------- Kernel 1: QKV projection (fp32 GEMM, bf16 output) ----------------
__global__ __launch_bounds__(256) void qkv_kernel(
    const float* __restrict__ x, const float* __restrict__ w,
    const float* __restrict__ bias,
    ushort_t* __restrict__ Q, ushort_t* __restrict__ K, ushort_t* __restrict__ V) {
  __shared__ float As[16][68];
  __shared__ float Bs[16][68];
  int t = threadIdx.x;
  int bx = blockIdx.x % 12;   // col tile (64 cols of 768)
  int by = blockIdx.x / 12;   // row tile (64 rows of 16384)
  int m0 = by * 64, j0 = bx * 64;
  int tx = t & 15, ty = t >> 4;
  float4 c4[4];
  #pragma unroll
  for (int i = 0; i < 4; i++) { c4[i].x = 0.f; c4[i].y = 0.f; c4[i].z = 0.f; c4[i].w = 0.f; }
  int skk = t & 15, sbase = t >> 4;
  for (int kc = 0; kc < 256; kc += 16) {
    __syncthreads();
    #pragma unroll
    for (int i = 0; i < 4; i++) {
      int mm = sbase + 16 * i;
      As[skk][mm] = x[(m0 + mm) * 256 + kc + skk];
      Bs[skk][mm] = w[(j0 + mm) * 256 + kc + skk];
    }
    __syncthreads();
    #pragma unroll
    for (int k2 = 0; k2 < 16; k2++) {
      float4 bv = *(const float4*)&Bs[k2][tx * 4];
      #pragma unroll
      for (int i = 0; i < 4; i++) {
        float a = As[k2][ty * 4 + i];
        c4[i].x += a * bv.x; c4[i].y += a * bv.y; c4[i].z += a * bv.z; c4[i].w += a * bv.w;
      }
    }
  }
  int j = j0 + tx * 4;
  int which = j >> 8;           // 0=q 1=k 2=v
  int e0 = j & 255;
  int h = e0 >> 5, d0 = e0 & 31;
  ushort_t* dst = (which == 0) ? Q : ((which == 1) ? K : V);
  float4 b4 = *(const float4*)&bias[j];
  #pragma unroll
  for (int i = 0; i < 4; i++) {
    int m = m0 + ty * 4 + i;
    int bi = m >> 9, n = m & 511;
    float fx = c4[i].x + b4.x, fy = c4[i].y + b4.y, fz = c4[i].z + b4.z, fw = c4[i].w + b4.w;
    uint_t lo = (uint_t)f2bf(fx) | ((uint_t)f2bf(fy) << 16);
    uint_t hi = (uint_t)f2bf(fz) | ((uint_t)f2bf(fw) << 16);
    uint2 pk; pk.x = lo; pk.y = hi;
    *(uint2*)&dst[(((size_t)(bi * 8 + h) * 512 + n) * 32) + d0] = pk;
  }
}

// ---------------- Kernel 2: MFMA bf16 attention ----------------
// block = (b, 16-query tile), 256 threads = 4 waves; wave w owns keys [w*128, w*128+128)
__global__ __launch_bounds__(256) void attn_kernel(
    const ushort_t* __restrict__ Q, const ushort_t* __restrict__ K,
    const ushort_t* __restrict__ V, const int* __restrict__ pre_mask,
    float* __restrict__ o, float* __restrict__ attnw) {
  __shared__ ushort_t sQ[16 * 32];          // 1 KB
  __shared__ ushort_t sP[16 * 520];         // 16.6 KB, padded rows (1040 B, 16B-aligned)
  __shared__ float sSum[4][16];             // per-wave row sums
  __shared__ float sO[4][16 * 32];          // per-wave PV partials, 8 KB

  int t = threadIdx.x;
  int bb = blockIdx.x >> 5;
  int q0 = (blockIdx.x & 31) << 4;
  int w = t >> 6;
  int lane = t & 63;
  int quad = lane >> 4;
  int l16 = lane & 15;
  int kbase = w * 128;
  const float scale = 0.17677669529663687f;  // 1/sqrt(32)

  float wmean[4][8];   // [reg(row=quad*4+reg)][tile] ; col = kbase + tile*16 + l16
  #pragma unroll
  for (int i = 0; i < 4; i++)
    #pragma unroll
    for (int j = 0; j < 8; j++) wmean[i][j] = 0.f;

  for (int h = 0; h < 8; h++) {
    size_t base = ((size_t)(bb * 8 + h) * 512) * 32;
    const ushort_t* Kg = K + base;
    const ushort_t* Vg = V + base;
    const int* mbase = pre_mask + ((size_t)(bb * 8 + h) * 512 + q0) * 512;

    // stage Q tile: 16 rows x 32 = contiguous 512 ushorts
    if (t < 64) {
      ((s16x8*)sQ)[t] = ((const s16x8*)(Q + base + (size_t)q0 * 32))[t];
    }
    __syncthreads();   // B1: sQ ready; prior-iter epilogue reads done

    // ---- QK^T scores for this wave's 128 keys (8 n-tiles) ----
    s16x8 afrag = *(const s16x8*)&sQ[l16 * 32 + quad * 8];
    float ev[8][4];
    #pragma unroll
    for (int t8 = 0; t8 < 8; t8++) {
      int n0 = kbase + t8 * 16;
      s16x8 bfrag = *(const s16x8*)&Kg[(size_t)(n0 + l16) * 32 + quad * 8];
      f32x4 acc = {0.f, 0.f, 0.f, 0.f};
      acc = __builtin_amdgcn_mfma_f32_16x16x32_bf16(afrag, bfrag, acc, 0, 0, 0);
      #pragma unroll
      for (int i = 0; i < 4; i++) {
        int msk = mbase[(quad * 4 + i) * 512 + n0 + l16];
        // scores bounded (|s|<~5): exp cannot overflow; masked -> weight 0 exactly
        ev[t8][i] = msk ? 0.f : __expf(acc[i] * scale);
      }
    }
    // partial row sums over this wave's 128 keys
    float ps[4];
    #pragma unroll
    for (int i = 0; i < 4; i++) {
      float s = 0.f;
      #pragma unroll
      for (int t8 = 0; t8 < 8; t8++) s += ev[t8][i];
      s += __shfl_xor(s, 1, 64);
      s += __shfl_xor(s, 2, 64);
      s += __shfl_xor(s, 4, 64);
      s += __shfl_xor(s, 8, 64);
      ps[i] = s;
    }
    if (l16 == 0) {
      #pragma unroll
      for (int i = 0; i < 4; i++) sSum[w][quad * 4 + i] = ps[i];
    }
    // write P (unnormalized e) to LDS in A-operand-friendly row-major [16][512]
    #pragma unroll
    for (int t8 = 0; t8 < 8; t8++)
      #pragma unroll
      for (int i = 0; i < 4; i++)
        sP[(quad * 4 + i) * 520 + kbase + t8 * 16 + l16] = f2bf(ev[t8][i]);
    __syncthreads();   // B2: sP, sSum ready

    // total row sums; accumulate head-mean weights
    float inv[4];
    #pragma unroll
    for (int i = 0; i < 4; i++) {
      int r = quad * 4 + i;
      inv[i] = 1.0f / (sSum[0][r] + sSum[1][r] + sSum[2][r] + sSum[3][r]);
    }
    #pragma unroll
    for (int t8 = 0; t8 < 8; t8++)
      #pragma unroll
      for (int i = 0; i < 4; i++)
        wmean[i][t8] += 0.125f * ev[t8][i] * inv[i];

    // ---- PV over this wave's 128 keys (unnormalized e), 2 d-tiles ----
    f32x4 oacc[2];
    oacc[0] = (f32x4){0.f, 0.f, 0.f, 0.f};
    oacc[1] = (f32x4){0.f, 0.f, 0.f, 0.f};
    #pragma unroll
    for (int ks = 0; ks < 4; ks++) {
      s16x8 pa = *(const s16x8*)&sP[l16 * 520 + kbase + ks * 32 + quad * 8];
      #pragma unroll
      for (int dt = 0; dt < 2; dt++) {
        s16x8 vb;
        #pragma unroll
        for (int j = 0; j < 8; j++)
          vb[j] = (short)Vg[(size_t)(kbase + ks * 32 + quad * 8 + j) * 32 + dt * 16 + l16];
        oacc[dt] = __builtin_amdgcn_mfma_f32_16x16x32_bf16(pa, vb, oacc[dt], 0, 0, 0);
      }
    }
    #pragma unroll
    for (int dt = 0; dt < 2; dt++)
      #pragma unroll
      for (int i = 0; i < 4; i++)
        sO[w][(quad * 4 + i) * 32 + dt * 16 + l16] = oacc[dt][i];
    __syncthreads();   // B3: sO ready

    // ---- epilogue: o[16][32] = (sum over waves) / rowsum ----
    {
      int r = t >> 4;            // 0..15
      int c = (t & 15) * 2;      // 0..30
      float s0 = sO[0][r * 32 + c] + sO[1][r * 32 + c] + sO[2][r * 32 + c] + sO[3][r * 32 + c];
      float s1 = sO[0][r * 32 + c + 1] + sO[1][r * 32 + c + 1] + sO[2][r * 32 + c + 1] + sO[3][r * 32 + c + 1];
      float invr = 1.0f / (sSum[0][r] + sSum[1][r] + sSum[2][r] + sSum[3][r]);
      float2 ov; ov.x = s0 * invr; ov.y = s1 * invr;
      *(float2*)&o[((size_t)(bb * 512 + q0 + r) * 256) + h * 32 + c] = ov;
    }
  }

  // ---- head-averaged attention weights ----
  float* arow = attnw + (size_t)(bb * 512 + q0) * 512;
  #pragma unroll
  for (int i = 0; i < 4; i++)
    #pragma unroll
    for (int t8 = 0; t8 < 8; t8++)
      arow[(quad * 4 + i) * 512 + kbase + t8 * 16 + l16] = wmean[i][t8];
}

// ---------------- Kernel 3: out-proj + post-mask + residual + LayerNorm ----------------
__global__ __launch_bounds__(256) void proj_ln_kernel(
    const float* __restrict__ x, const float* __restrict__ w,
    const float* __restrict__ bias, const int* __restrict__ post_mask,
    const float* __restrict__ gamma, const float* __restrict__ beta,
    float* __restrict__ io /* o in, final out, in place */) {
  __shared__ float As[16][17];
  __shared__ float Bs[16][260];
  int t = threadIdx.x;
  int m0 = blockIdx.x * 16;
  int tx = t & 63, ty = t >> 6;
  float4 c4[4];
  #pragma unroll
  for (int i = 0; i < 4; i++) { c4[i].x = 0.f; c4[i].y = 0.f; c4[i].z = 0.f; c4[i].w = 0.f; }
  int skk = t & 15, srr = t >> 4;
  for (int kc = 0; kc < 256; kc += 16) {
    __syncthreads();
    As[skk][srr] = io[(m0 + srr) * 256 + kc + skk];
    #pragma unroll
    for (int i = 0; i < 16; i++) {
      int idx = t + i * 256;
      int kk = idx & 15, jj = idx >> 4;
      Bs[kk][jj] = w[jj * 256 + kc + kk];
    }
    __syncthreads();
    #pragma unroll
    for (int k2 = 0; k2 < 16; k2++) {
      float4 bv = *(const float4*)&Bs[k2][tx * 4];
      #pragma unroll
      for (int i = 0; i < 4; i++) {
        float a = As[k2][ty * 4 + i];
        c4[i].x += a * bv.x; c4[i].y += a * bv.y; c4[i].z += a * bv.z; c4[i].w += a * bv.w;
      }
    }
  }
  int j0 = tx * 4;
  float4 gm = *(const float4*)&gamma[j0];
  float4 bt = *(const float4*)&beta[j0];
  float4 ob = *(const float4*)&bias[j0];
  float4 yv[4];
  float s1[4], s2[4];
  #pragma unroll
  for (int i = 0; i < 4; i++) {
    int m = m0 + ty * 4 + i;
    int bi = m >> 9, n = m & 511;
    bool msk = post_mask[bi * 512 + n] != 0;
    float4 xv = *(const float4*)&x[m * 256 + j0];
    float4 pv;
    pv.x = msk ? 0.f : c4[i].x + ob.x;
    pv.y = msk ? 0.f : c4[i].y + ob.y;
    pv.z = msk ? 0.f : c4[i].z + ob.z;
    pv.w = msk ? 0.f : c4[i].w + ob.w;
    float4 y;
    y.x = xv.x + pv.x; y.y = xv.y + pv.y; y.z = xv.z + pv.z; y.w = xv.w + pv.w;
    yv[i] = y;
    s1[i] = y.x + y.y + y.z + y.w;
    s2[i] = y.x * y.x + y.y * y.y + y.z * y.z + y.w * y.w;
  }
  #pragma unroll
  for (int off = 32; off > 0; off >>= 1) {
    #pragma unroll
    for (int i = 0; i < 4; i++) {
      s1[i] += __shfl_xor(s1[i], off, 64);
      s2[i] += __shfl_xor(s2[i], off, 64);
    }
  }
  #pragma unroll
  for (int i = 0; i < 4; i++) {
    int m = m0 + ty * 4 + i;
    float mu = s1[i] * (1.0f / 256.0f);
    float var = s2[i] * (1.0f / 256.0f) - mu * mu;
    float rstd = rsqrtf(var + 1e-5f);
    float4 y = yv[i];
    float4 outv;
    outv.x = (y.x - mu) * rstd * gm.x + bt.x;
    outv.y = (y.y - mu) * rstd * gm.y + bt.y;
    outv.z = (y.z - mu) * rstd * gm.z + bt.z;
    outv.w = (y.w - mu) * rstd * gm.w + bt.w;
    *(float4*)&io[m * 256 + j0] = outv;
  }
}

extern "C" void kernel_launch(void* const* d_in, const int* in_sizes, int n_in,
                              void* d_out, int out_size, void* d_ws, size_t ws_size,
                              hipStream_t stream) {
  const float* x       = (const float*)d_in[0];
  const int*   pre_m   = (const int*)d_in[1];
  const int*   post_m  = (const int*)d_in[2];
  const float* in_w    = (const float*)d_in[3];
  const float* in_b    = (const float*)d_in[4];
  const float* out_w   = (const float*)d_in[5];
  const float* out_b   = (const float*)d_in[6];
  const float* gamma   = (const float*)d_in[7];
  const float* beta    = (const float*)d_in[8];
  float* out   = (float*)d_out;                       // [B,N,E]
  float* attnw = out + (size_t)BB * NN * EE;          // [B,N,N]
  ushort_t* Q = (ushort_t*)d_ws;                      // bf16 [B,H,N,32] each
  ushort_t* K = Q + (size_t)BB * HH * NN * HDD;
  ushort_t* V = K + (size_t)BB * HH * NN * HDD;

  qkv_kernel<<<dim3(3072), dim3(256), 0, stream>>>(x, in_w, in_b, Q, K, V);
  attn_kernel<<<dim3(1024), dim3(256), 0, stream>>>(Q, K, V, pre_m, out, attnw);
  proj_ln_kernel<<<dim3(1024), dim3(256), 0, stream>>>(x, out_w, out_b, post_m, gamma, beta, out);
}

// Round 3
// 503.564 us; speedup vs baseline: 2.2908x; 1.0806x over previous
//
#include <hip/hip_runtime.h>

#define BB 32
#define NN 512
#define EE 256
#define HH 8
#define HDD 32

typedef __attribute__((ext_vector_type(4))) float f32x4;
typedef __attribute__((ext_vector_type(8))) short s16x8;
typedef unsigned short ushort_t;
typedef unsigned int uint_t;

__device__ __forceinline__ ushort_t f2bf(float f) {
  union { float f; uint_t u; } v; v.f = f;
  uint_t r = v.u + 0x7fffu + ((v.u >> 16) & 1u);
  return (ushort_t)(r >> 16);
}
__device__ __forceinline__ uint_t pk2(float a, float b) {
  return (uint_t)f2bf(a) | ((uint_t)f2bf(b) << 16);
}

// ---------------- Kernel 1: QKV projection (bf16 MFMA GEMM) ----------------
// C[m][j] = sum_k x[m][k]*w[j][k] + b[j];  M=16384, N=768, K=256
// 128x128 tile, 4 waves 2x2, each wave 64x64 = 4x4 16x16 tiles, BK=32
__global__ __launch_bounds__(256) void qkv_mfma(
    const float* __restrict__ x, const float* __restrict__ w,
    const float* __restrict__ bias,
    ushort_t* __restrict__ Q, ushort_t* __restrict__ K, ushort_t* __restrict__ V) {
  __shared__ ushort_t sA[128][40];   // 10 KB, padded
  __shared__ ushort_t sB[128][40];
  int t = threadIdx.x;
  int bj = blockIdx.x % 6, bm = blockIdx.x / 6;
  int m0 = bm * 128, j0 = bj * 128;
  int w4 = t >> 6, lane = t & 63, quad = lane >> 4, l16 = lane & 15;
  int wy = w4 >> 1, wx = w4 & 1;
  f32x4 acc[4][4];
  #pragma unroll
  for (int a = 0; a < 4; a++)
    #pragma unroll
    for (int b = 0; b < 4; b++) acc[a][b] = (f32x4){0.f, 0.f, 0.f, 0.f};
  int sr = t >> 3, sc = t & 7;       // staging: row sr+32i, float4 col sc
  for (int kk = 0; kk < 256; kk += 32) {
    __syncthreads();
    #pragma unroll
    for (int i = 0; i < 4; i++) {
      int r = sr + 32 * i;
      float4 av = *(const float4*)&x[(size_t)(m0 + r) * 256 + kk + sc * 4];
      float4 bv = *(const float4*)&w[(size_t)(j0 + r) * 256 + kk + sc * 4];
      uint2 pa; pa.x = pk2(av.x, av.y); pa.y = pk2(av.z, av.w);
      uint2 pb; pb.x = pk2(bv.x, bv.y); pb.y = pk2(bv.z, bv.w);
      *(uint2*)&sA[r][sc * 4] = pa;
      *(uint2*)&sB[r][sc * 4] = pb;
    }
    __syncthreads();
    s16x8 af[4], bf[4];
    #pragma unroll
    for (int mt = 0; mt < 4; mt++)
      af[mt] = *(const s16x8*)&sA[wy * 64 + mt * 16 + l16][quad * 8];
    #pragma unroll
    for (int jt = 0; jt < 4; jt++)
      bf[jt] = *(const s16x8*)&sB[wx * 64 + jt * 16 + l16][quad * 8];
    #pragma unroll
    for (int mt = 0; mt < 4; mt++)
      #pragma unroll
      for (int jt = 0; jt < 4; jt++)
        acc[mt][jt] = __builtin_amdgcn_mfma_f32_16x16x32_bf16(af[mt], bf[jt], acc[mt][jt], 0, 0, 0);
  }
  // epilogue: scatter to head-major bf16 Q/K/V
  #pragma unroll
  for (int jt = 0; jt < 4; jt++) {
    int j = j0 + wx * 64 + jt * 16 + l16;
    int which = j >> 8, e0 = j & 255, h = e0 >> 5, d0 = e0 & 31;
    ushort_t* dst = (which == 0) ? Q : ((which == 1) ? K : V);
    float b = bias[j];
    #pragma unroll
    for (int mt = 0; mt < 4; mt++) {
      #pragma unroll
      for (int r = 0; r < 4; r++) {
        int m = m0 + wy * 64 + mt * 16 + quad * 4 + r;
        int bi = m >> 9, n = m & 511;
        dst[((size_t)(bi * 8 + h) * 512 + n) * 32 + d0] = f2bf(acc[mt][jt][r] + b);
      }
    }
  }
}

// ---------------- Kernel 2: MFMA bf16 attention ----------------
// block = (b, 16-query tile), 4 waves; wave w owns keys [w*128, w*128+128)
__global__ __launch_bounds__(256) void attn_kernel(
    const ushort_t* __restrict__ Q, const ushort_t* __restrict__ K,
    const ushort_t* __restrict__ V, const int* __restrict__ pre_mask,
    ushort_t* __restrict__ O, float* __restrict__ attnw) {
  __shared__ ushort_t sQ[16 * 32];          // 1 KB
  __shared__ ushort_t sP[16 * 520];         // 16.6 KB padded
  __shared__ float sSum[4][16];
  __shared__ float sO[4][16 * 32];          // 8 KB

  int t = threadIdx.x;
  int bb = blockIdx.x >> 5;
  int q0 = (blockIdx.x & 31) << 4;
  int w = t >> 6;
  int lane = t & 63;
  int quad = lane >> 4;
  int l16 = lane & 15;
  int kbase = w * 128;
  const float scale = 0.17677669529663687f;  // 1/sqrt(32)

  float wmean[4][8];
  #pragma unroll
  for (int i = 0; i < 4; i++)
    #pragma unroll
    for (int j = 0; j < 8; j++) wmean[i][j] = 0.f;

  for (int h = 0; h < 8; h++) {
    size_t base = ((size_t)(bb * 8 + h) * 512) * 32;
    const ushort_t* Kg = K + base;
    const ushort_t* Vg = V + base;
    const int* mbase = pre_mask + ((size_t)(bb * 8 + h) * 512 + q0) * 512;

    if (t < 64) {
      ((s16x8*)sQ)[t] = ((const s16x8*)(Q + base + (size_t)q0 * 32))[t];
    }
    __syncthreads();   // B1

    s16x8 afrag = *(const s16x8*)&sQ[l16 * 32 + quad * 8];
    float ev[8][4];
    #pragma unroll
    for (int t8 = 0; t8 < 8; t8++) {
      int n0 = kbase + t8 * 16;
      s16x8 bfrag = *(const s16x8*)&Kg[(size_t)(n0 + l16) * 32 + quad * 8];
      f32x4 acc = {0.f, 0.f, 0.f, 0.f};
      acc = __builtin_amdgcn_mfma_f32_16x16x32_bf16(afrag, bfrag, acc, 0, 0, 0);
      #pragma unroll
      for (int i = 0; i < 4; i++) {
        int msk = mbase[(quad * 4 + i) * 512 + n0 + l16];
        ev[t8][i] = msk ? 0.f : __expf(acc[i] * scale);
      }
    }
    float ps[4];
    #pragma unroll
    for (int i = 0; i < 4; i++) {
      float s = 0.f;
      #pragma unroll
      for (int t8 = 0; t8 < 8; t8++) s += ev[t8][i];
      s += __shfl_xor(s, 1, 64);
      s += __shfl_xor(s, 2, 64);
      s += __shfl_xor(s, 4, 64);
      s += __shfl_xor(s, 8, 64);
      ps[i] = s;
    }
    if (l16 == 0) {
      #pragma unroll
      for (int i = 0; i < 4; i++) sSum[w][quad * 4 + i] = ps[i];
    }
    #pragma unroll
    for (int t8 = 0; t8 < 8; t8++)
      #pragma unroll
      for (int i = 0; i < 4; i++)
        sP[(quad * 4 + i) * 520 + kbase + t8 * 16 + l16] = f2bf(ev[t8][i]);
    __syncthreads();   // B2

    float inv[4];
    #pragma unroll
    for (int i = 0; i < 4; i++) {
      int r = quad * 4 + i;
      inv[i] = 1.0f / (sSum[0][r] + sSum[1][r] + sSum[2][r] + sSum[3][r]);
    }
    #pragma unroll
    for (int t8 = 0; t8 < 8; t8++)
      #pragma unroll
      for (int i = 0; i < 4; i++)
        wmean[i][t8] += 0.125f * ev[t8][i] * inv[i];

    f32x4 oacc[2];
    oacc[0] = (f32x4){0.f, 0.f, 0.f, 0.f};
    oacc[1] = (f32x4){0.f, 0.f, 0.f, 0.f};
    #pragma unroll
    for (int ks = 0; ks < 4; ks++) {
      s16x8 pa = *(const s16x8*)&sP[l16 * 520 + kbase + ks * 32 + quad * 8];
      #pragma unroll
      for (int dt = 0; dt < 2; dt++) {
        s16x8 vb;
        #pragma unroll
        for (int j = 0; j < 8; j++)
          vb[j] = (short)Vg[(size_t)(kbase + ks * 32 + quad * 8 + j) * 32 + dt * 16 + l16];
        oacc[dt] = __builtin_amdgcn_mfma_f32_16x16x32_bf16(pa, vb, oacc[dt], 0, 0, 0);
      }
    }
    #pragma unroll
    for (int dt = 0; dt < 2; dt++)
      #pragma unroll
      for (int i = 0; i < 4; i++)
        sO[w][(quad * 4 + i) * 32 + dt * 16 + l16] = oacc[dt][i];
    __syncthreads();   // B3

    {
      int r = t >> 4;
      int c = (t & 15) * 2;
      float s0 = sO[0][r * 32 + c] + sO[1][r * 32 + c] + sO[2][r * 32 + c] + sO[3][r * 32 + c];
      float s1 = sO[0][r * 32 + c + 1] + sO[1][r * 32 + c + 1] + sO[2][r * 32 + c + 1] + sO[3][r * 32 + c + 1];
      float invr = 1.0f / (sSum[0][r] + sSum[1][r] + sSum[2][r] + sSum[3][r]);
      uint_t pk = pk2(s0 * invr, s1 * invr);
      *(uint_t*)&O[((size_t)(bb * 512 + q0 + r) * 256) + h * 32 + c] = pk;
    }
  }

  float* arow = attnw + (size_t)(bb * 512 + q0) * 512;
  #pragma unroll
  for (int i = 0; i < 4; i++)
    #pragma unroll
    for (int t8 = 0; t8 < 8; t8++)
      arow[(quad * 4 + i) * 512 + kbase + t8 * 16 + l16] = wmean[i][t8];
}

// ---------------- Kernel 3: out-proj MFMA + mask + residual + LayerNorm ----------------
// C[m][j] = sum_k O[m][k]*w[j][k];  64-row x 256-col tile, wave = 16 rows x 256 cols
__global__ __launch_bounds__(256) void proj_ln_mfma(
    const ushort_t* __restrict__ O, const float* __restrict__ x,
    const float* __restrict__ w, const float* __restrict__ bias,
    const int* __restrict__ post_mask,
    const float* __restrict__ gamma, const float* __restrict__ beta,
    float* __restrict__ out) {
  __shared__ ushort_t sB[256][40];   // 20 KB
  int t = threadIdx.x;
  int m0 = blockIdx.x * 64;
  int w4 = t >> 6, lane = t & 63, quad = lane >> 4, l16 = lane & 15;
  int mrow0 = m0 + w4 * 16;
  f32x4 acc[16];
  #pragma unroll
  for (int jt = 0; jt < 16; jt++) acc[jt] = (f32x4){0.f, 0.f, 0.f, 0.f};
  int sr = t >> 3, sc = t & 7;
  for (int kk = 0; kk < 256; kk += 32) {
    __syncthreads();
    #pragma unroll
    for (int i = 0; i < 8; i++) {
      int r = sr + 32 * i;
      float4 bv = *(const float4*)&w[(size_t)r * 256 + kk + sc * 4];
      uint2 pb; pb.x = pk2(bv.x, bv.y); pb.y = pk2(bv.z, bv.w);
      *(uint2*)&sB[r][sc * 4] = pb;
    }
    __syncthreads();
    s16x8 af = *(const s16x8*)&O[(size_t)(mrow0 + l16) * 256 + kk + quad * 8];
    #pragma unroll
    for (int jt = 0; jt < 16; jt++) {
      s16x8 bf = *(const s16x8*)&sB[jt * 16 + l16][quad * 8];
      acc[jt] = __builtin_amdgcn_mfma_f32_16x16x32_bf16(af, bf, acc[jt], 0, 0, 0);
    }
  }
  // epilogue: rows mrow0+quad*4+i; lane holds cols jt*16+l16
  #pragma unroll
  for (int i = 0; i < 4; i++) {
    int m = mrow0 + quad * 4 + i;
    int bi = m >> 9, n = m & 511;
    bool msk = post_mask[bi * 512 + n] != 0;
    float y[16];
    float s1 = 0.f, s2 = 0.f;
    #pragma unroll
    for (int jt = 0; jt < 16; jt++) {
      int j = jt * 16 + l16;
      float p = msk ? 0.f : (acc[jt][i] + bias[j]);
      float yy = x[(size_t)m * 256 + j] + p;
      y[jt] = yy; s1 += yy; s2 += yy * yy;
    }
    s1 += __shfl_xor(s1, 1, 64); s1 += __shfl_xor(s1, 2, 64);
    s1 += __shfl_xor(s1, 4, 64); s1 += __shfl_xor(s1, 8, 64);
    s2 += __shfl_xor(s2, 1, 64); s2 += __shfl_xor(s2, 2, 64);
    s2 += __shfl_xor(s2, 4, 64); s2 += __shfl_xor(s2, 8, 64);
    float mu = s1 * (1.0f / 256.0f);
    float var = s2 * (1.0f / 256.0f) - mu * mu;
    float rstd = rsqrtf(var + 1e-5f);
    #pragma unroll
    for (int jt = 0; jt < 16; jt++) {
      int j = jt * 16 + l16;
      out[(size_t)m * 256 + j] = (y[jt] - mu) * rstd * gamma[j] + beta[j];
    }
  }
}

extern "C" void kernel_launch(void* const* d_in, const int* in_sizes, int n_in,
                              void* d_out, int out_size, void* d_ws, size_t ws_size,
                              hipStream_t stream) {
  const float* x       = (const float*)d_in[0];
  const int*   pre_m   = (const int*)d_in[1];
  const int*   post_m  = (const int*)d_in[2];
  const float* in_w    = (const float*)d_in[3];
  const float* in_b    = (const float*)d_in[4];
  const float* out_w   = (const float*)d_in[5];
  const float* out_b   = (const float*)d_in[6];
  const float* gamma   = (const float*)d_in[7];
  const float* beta    = (const float*)d_in[8];
  float* out   = (float*)d_out;                       // [B,N,E]
  float* attnw = out + (size_t)BB * NN * EE;          // [B,N,N]
  ushort_t* Q = (ushort_t*)d_ws;                      // bf16 [B,H,N,32] each
  ushort_t* K = Q + (size_t)BB * HH * NN * HDD;
  ushort_t* V = K + (size_t)BB * HH * NN * HDD;
  ushort_t* O = V + (size_t)BB * HH * NN * HDD;       // bf16 [B*N, E]

  qkv_mfma<<<dim3(768), dim3(256), 0, stream>>>(x, in_w, in_b, Q, K, V);
  attn_kernel<<<dim3(1024), dim3(256), 0, stream>>>(Q, K, V, pre_m, O, attnw);
  proj_ln_mfma<<<dim3(256), dim3(256), 0, stream>>>(O, x, out_w, out_b, post_m, gamma, beta, out);
}

// Round 4
// 486.389 us; speedup vs baseline: 2.3717x; 1.0353x over previous
//
#include <hip/hip_runtime.h>

#define BB 32
#define NN 512
#define EE 256
#define HH 8
#define HDD 32

typedef __attribute__((ext_vector_type(4))) float f32x4;
typedef __attribute__((ext_vector_type(8))) short s16x8;
typedef unsigned short ushort_t;
typedef unsigned int uint_t;

__device__ __forceinline__ ushort_t f2bf(float f) {
  union { float f; uint_t u; } v; v.f = f;
  uint_t r = v.u + 0x7fffu + ((v.u >> 16) & 1u);
  return (ushort_t)(r >> 16);
}
__device__ __forceinline__ uint_t pk2(float a, float b) {
  return (uint_t)f2bf(a) | ((uint_t)f2bf(b) << 16);
}

// ---------------- Kernel 0: fp32 -> bf16 convert (x, in_w, out_w) ----------------
__global__ __launch_bounds__(256) void cvt_bf16(
    const float* __restrict__ src, ushort_t* __restrict__ dst, int n4) {
  int i = blockIdx.x * 256 + threadIdx.x;
  if (i < n4) {
    float4 v = ((const float4*)src)[i];
    uint2 p; p.x = pk2(v.x, v.y); p.y = pk2(v.z, v.w);
    ((uint2*)dst)[i] = p;
  }
}

// ---------------- Kernel 1: QKV projection (bf16 MFMA GEMM) ----------------
// C[m][j] = sum_k x[m][k]*w[j][k] + b[j];  M=16384, N=768, K=256
// 128x128 tile, 4 waves 2x2, BK=32. V stored transposed: Vt[B,H,32,512].
__global__ __launch_bounds__(256) void qkv_mfma(
    const ushort_t* __restrict__ xb, const ushort_t* __restrict__ wb,
    const float* __restrict__ bias,
    ushort_t* __restrict__ Q, ushort_t* __restrict__ K, ushort_t* __restrict__ Vt) {
  __shared__ ushort_t sA[128][40];   // padded
  __shared__ ushort_t sB[128][40];
  int t = threadIdx.x;
  int bj = blockIdx.x % 6, bm = blockIdx.x / 6;
  int m0 = bm * 128, j0 = bj * 128;
  int w4 = t >> 6, lane = t & 63, quad = lane >> 4, l16 = lane & 15;
  int wy = w4 >> 1, wx = w4 & 1;
  f32x4 acc[4][4];
  #pragma unroll
  for (int a = 0; a < 4; a++)
    #pragma unroll
    for (int b = 0; b < 4; b++) acc[a][b] = (f32x4){0.f, 0.f, 0.f, 0.f};
  int sr2 = t >> 2, sc2 = (t & 3) * 8;   // 4 lanes/row, 8 bf16 each
  for (int kk = 0; kk < 256; kk += 32) {
    __syncthreads();
    #pragma unroll
    for (int p = 0; p < 2; p++) {
      int r = sr2 + 64 * p;
      *(s16x8*)&sA[r][sc2] = *(const s16x8*)&xb[(size_t)(m0 + r) * 256 + kk + sc2];
      *(s16x8*)&sB[r][sc2] = *(const s16x8*)&wb[(size_t)(j0 + r) * 256 + kk + sc2];
    }
    __syncthreads();
    s16x8 af[4], bf[4];
    #pragma unroll
    for (int mt = 0; mt < 4; mt++)
      af[mt] = *(const s16x8*)&sA[wy * 64 + mt * 16 + l16][quad * 8];
    #pragma unroll
    for (int jt = 0; jt < 4; jt++)
      bf[jt] = *(const s16x8*)&sB[wx * 64 + jt * 16 + l16][quad * 8];
    #pragma unroll
    for (int mt = 0; mt < 4; mt++)
      #pragma unroll
      for (int jt = 0; jt < 4; jt++)
        acc[mt][jt] = __builtin_amdgcn_mfma_f32_16x16x32_bf16(af[mt], bf[jt], acc[mt][jt], 0, 0, 0);
  }
  // epilogue: scatter; q,k head-major [B,H,N,32]; v transposed [B,H,32,512]
  #pragma unroll
  for (int jt = 0; jt < 4; jt++) {
    int j = j0 + wx * 64 + jt * 16 + l16;
    int which = j >> 8, e0 = j & 255, h = e0 >> 5, d0 = e0 & 31;
    float b = bias[j];
    #pragma unroll
    for (int mt = 0; mt < 4; mt++) {
      #pragma unroll
      for (int r = 0; r < 4; r++) {
        int m = m0 + wy * 64 + mt * 16 + quad * 4 + r;
        int bi = m >> 9, n = m & 511;
        ushort_t val = f2bf(acc[mt][jt][r] + b);
        if (which == 2) {
          Vt[((size_t)(bi * 8 + h) * 32 + d0) * 512 + n] = val;
        } else {
          ushort_t* dst = (which == 0) ? Q : K;
          dst[((size_t)(bi * 8 + h) * 512 + n) * 32 + d0] = val;
        }
      }
    }
  }
}

// ---------------- Kernel 2: MFMA bf16 attention ----------------
// block = (b, 16-query tile), 4 waves; wave w owns keys [w*128, w*128+128)
__global__ __launch_bounds__(256) void attn_kernel(
    const ushort_t* __restrict__ Q, const ushort_t* __restrict__ K,
    const ushort_t* __restrict__ Vt, const int* __restrict__ pre_mask,
    ushort_t* __restrict__ O, float* __restrict__ attnw) {
  __shared__ ushort_t sQ[16 * 32];          // 1 KB
  __shared__ ushort_t sP[16 * 520];         // 16.6 KB padded
  __shared__ float sSum[4][16];
  __shared__ float sO[4][16 * 32];          // 8 KB

  int t = threadIdx.x;
  int bb = blockIdx.x >> 5;
  int q0 = (blockIdx.x & 31) << 4;
  int w = t >> 6;
  int lane = t & 63;
  int quad = lane >> 4;
  int l16 = lane & 15;
  int kbase = w * 128;
  const float scale = 0.17677669529663687f;  // 1/sqrt(32)

  float wmean[4][8];
  #pragma unroll
  for (int i = 0; i < 4; i++)
    #pragma unroll
    for (int j = 0; j < 8; j++) wmean[i][j] = 0.f;

  for (int h = 0; h < 8; h++) {
    size_t base = ((size_t)(bb * 8 + h) * 512) * 32;
    const ushort_t* Kg = K + base;
    const ushort_t* Vg = Vt + base;   // transposed [32][512]
    const int* mbase = pre_mask + ((size_t)(bb * 8 + h) * 512 + q0) * 512;

    if (t < 64) {
      ((s16x8*)sQ)[t] = ((const s16x8*)(Q + base + (size_t)q0 * 32))[t];
    }
    __syncthreads();   // B1

    s16x8 afrag = *(const s16x8*)&sQ[l16 * 32 + quad * 8];
    float ev[8][4];
    #pragma unroll
    for (int t8 = 0; t8 < 8; t8++) {
      int n0 = kbase + t8 * 16;
      s16x8 bfrag = *(const s16x8*)&Kg[(size_t)(n0 + l16) * 32 + quad * 8];
      f32x4 acc = {0.f, 0.f, 0.f, 0.f};
      acc = __builtin_amdgcn_mfma_f32_16x16x32_bf16(afrag, bfrag, acc, 0, 0, 0);
      #pragma unroll
      for (int i = 0; i < 4; i++) {
        int msk = mbase[(quad * 4 + i) * 512 + n0 + l16];
        ev[t8][i] = msk ? 0.f : __expf(acc[i] * scale);
      }
    }
    float ps[4];
    #pragma unroll
    for (int i = 0; i < 4; i++) {
      float s = 0.f;
      #pragma unroll
      for (int t8 = 0; t8 < 8; t8++) s += ev[t8][i];
      s += __shfl_xor(s, 1, 64);
      s += __shfl_xor(s, 2, 64);
      s += __shfl_xor(s, 4, 64);
      s += __shfl_xor(s, 8, 64);
      ps[i] = s;
    }
    if (l16 == 0) {
      #pragma unroll
      for (int i = 0; i < 4; i++) sSum[w][quad * 4 + i] = ps[i];
    }
    #pragma unroll
    for (int t8 = 0; t8 < 8; t8++)
      #pragma unroll
      for (int i = 0; i < 4; i++)
        sP[(quad * 4 + i) * 520 + kbase + t8 * 16 + l16] = f2bf(ev[t8][i]);
    __syncthreads();   // B2

    float inv[4];
    #pragma unroll
    for (int i = 0; i < 4; i++) {
      int r = quad * 4 + i;
      inv[i] = 1.0f / (sSum[0][r] + sSum[1][r] + sSum[2][r] + sSum[3][r]);
    }
    #pragma unroll
    for (int t8 = 0; t8 < 8; t8++)
      #pragma unroll
      for (int i = 0; i < 4; i++)
        wmean[i][t8] += 0.125f * ev[t8][i] * inv[i];

    f32x4 oacc[2];
    oacc[0] = (f32x4){0.f, 0.f, 0.f, 0.f};
    oacc[1] = (f32x4){0.f, 0.f, 0.f, 0.f};
    #pragma unroll
    for (int ks = 0; ks < 4; ks++) {
      s16x8 pa = *(const s16x8*)&sP[l16 * 520 + kbase + ks * 32 + quad * 8];
      #pragma unroll
      for (int dt = 0; dt < 2; dt++) {
        s16x8 vb = *(const s16x8*)&Vg[(size_t)(dt * 16 + l16) * 512 + kbase + ks * 32 + quad * 8];
        oacc[dt] = __builtin_amdgcn_mfma_f32_16x16x32_bf16(pa, vb, oacc[dt], 0, 0, 0);
      }
    }
    #pragma unroll
    for (int dt = 0; dt < 2; dt++)
      #pragma unroll
      for (int i = 0; i < 4; i++)
        sO[w][(quad * 4 + i) * 32 + dt * 16 + l16] = oacc[dt][i];
    __syncthreads();   // B3

    {
      int r = t >> 4;
      int c = (t & 15) * 2;
      float s0 = sO[0][r * 32 + c] + sO[1][r * 32 + c] + sO[2][r * 32 + c] + sO[3][r * 32 + c];
      float s1 = sO[0][r * 32 + c + 1] + sO[1][r * 32 + c + 1] + sO[2][r * 32 + c + 1] + sO[3][r * 32 + c + 1];
      float invr = 1.0f / (sSum[0][r] + sSum[1][r] + sSum[2][r] + sSum[3][r]);
      uint_t pk = pk2(s0 * invr, s1 * invr);
      *(uint_t*)&O[((size_t)(bb * 512 + q0 + r) * 256) + h * 32 + c] = pk;
    }
  }

  float* arow = attnw + (size_t)(bb * 512 + q0) * 512;
  #pragma unroll
  for (int i = 0; i < 4; i++)
    #pragma unroll
    for (int t8 = 0; t8 < 8; t8++)
      arow[(quad * 4 + i) * 512 + kbase + t8 * 16 + l16] = wmean[i][t8];
}

// ---------------- Kernel 3: out-proj MFMA + mask + residual + LayerNorm ----------------
__global__ __launch_bounds__(256) void proj_ln_mfma(
    const ushort_t* __restrict__ O, const float* __restrict__ x,
    const ushort_t* __restrict__ wb, const float* __restrict__ bias,
    const int* __restrict__ post_mask,
    const float* __restrict__ gamma, const float* __restrict__ beta,
    float* __restrict__ out) {
  __shared__ ushort_t sB[256][40];   // 20 KB
  int t = threadIdx.x;
  int m0 = blockIdx.x * 64;
  int w4 = t >> 6, lane = t & 63, quad = lane >> 4, l16 = lane & 15;
  int mrow0 = m0 + w4 * 16;
  f32x4 acc[16];
  #pragma unroll
  for (int jt = 0; jt < 16; jt++) acc[jt] = (f32x4){0.f, 0.f, 0.f, 0.f};
  int sr2 = t >> 2, sc2 = (t & 3) * 8;
  for (int kk = 0; kk < 256; kk += 32) {
    __syncthreads();
    #pragma unroll
    for (int p = 0; p < 4; p++) {
      int r = sr2 + 64 * p;
      *(s16x8*)&sB[r][sc2] = *(const s16x8*)&wb[(size_t)r * 256 + kk + sc2];
    }
    __syncthreads();
    s16x8 af = *(const s16x8*)&O[(size_t)(mrow0 + l16) * 256 + kk + quad * 8];
    #pragma unroll
    for (int jt = 0; jt < 16; jt++) {
      s16x8 bf = *(const s16x8*)&sB[jt * 16 + l16][quad * 8];
      acc[jt] = __builtin_amdgcn_mfma_f32_16x16x32_bf16(af, bf, acc[jt], 0, 0, 0);
    }
  }
  #pragma unroll
  for (int i = 0; i < 4; i++) {
    int m = mrow0 + quad * 4 + i;
    int bi = m >> 9, n = m & 511;
    bool msk = post_mask[bi * 512 + n] != 0;
    float y[16];
    float s1 = 0.f, s2 = 0.f;
    #pragma unroll
    for (int jt = 0; jt < 16; jt++) {
      int j = jt * 16 + l16;
      float p = msk ? 0.f : (acc[jt][i] + bias[j]);
      float yy = x[(size_t)m * 256 + j] + p;
      y[jt] = yy; s1 += yy; s2 += yy * yy;
    }
    s1 += __shfl_xor(s1, 1, 64); s1 += __shfl_xor(s1, 2, 64);
    s1 += __shfl_xor(s1, 4, 64); s1 += __shfl_xor(s1, 8, 64);
    s2 += __shfl_xor(s2, 1, 64); s2 += __shfl_xor(s2, 2, 64);
    s2 += __shfl_xor(s2, 4, 64); s2 += __shfl_xor(s2, 8, 64);
    float mu = s1 * (1.0f / 256.0f);
    float var = s2 * (1.0f / 256.0f) - mu * mu;
    float rstd = rsqrtf(var + 1e-5f);
    #pragma unroll
    for (int jt = 0; jt < 16; jt++) {
      int j = jt * 16 + l16;
      out[(size_t)m * 256 + j] = (y[jt] - mu) * rstd * gamma[j] + beta[j];
    }
  }
}

extern "C" void kernel_launch(void* const* d_in, const int* in_sizes, int n_in,
                              void* d_out, int out_size, void* d_ws, size_t ws_size,
                              hipStream_t stream) {
  const float* x       = (const float*)d_in[0];
  const int*   pre_m   = (const int*)d_in[1];
  const int*   post_m  = (const int*)d_in[2];
  const float* in_w    = (const float*)d_in[3];
  const float* in_b    = (const float*)d_in[4];
  const float* out_w   = (const float*)d_in[5];
  const float* out_b   = (const float*)d_in[6];
  const float* gamma   = (const float*)d_in[7];
  const float* beta    = (const float*)d_in[8];
  float* out   = (float*)d_out;                       // [B,N,E]
  float* attnw = out + (size_t)BB * NN * EE;          // [B,N,N]
  ushort_t* Q  = (ushort_t*)d_ws;                     // bf16 [B,H,N,32]
  ushort_t* K  = Q  + (size_t)BB * HH * NN * HDD;     // bf16 [B,H,N,32]
  ushort_t* Vt = K  + (size_t)BB * HH * NN * HDD;     // bf16 [B,H,32,N] (transposed)
  ushort_t* O  = Vt + (size_t)BB * HH * NN * HDD;     // bf16 [B*N, E]
  ushort_t* xb  = O  + (size_t)BB * NN * EE;          // bf16 [B*N, E]
  ushort_t* wib = xb + (size_t)BB * NN * EE;          // bf16 [768, 256]
  ushort_t* wob = wib + (size_t)3 * EE * EE;          // bf16 [256, 256]

  cvt_bf16<<<dim3(4096), dim3(256), 0, stream>>>(x, xb, BB * NN * EE / 4);
  cvt_bf16<<<dim3(192), dim3(256), 0, stream>>>(in_w, wib, 3 * EE * EE / 4);
  cvt_bf16<<<dim3(64), dim3(256), 0, stream>>>(out_w, wob, EE * EE / 4);
  qkv_mfma<<<dim3(768), dim3(256), 0, stream>>>(xb, wib, in_b, Q, K, Vt);
  attn_kernel<<<dim3(1024), dim3(256), 0, stream>>>(Q, K, Vt, pre_m, O, attnw);
  proj_ln_mfma<<<dim3(256), dim3(256), 0, stream>>>(O, x, wob, out_b, post_m, gamma, beta, out);
}

// Round 5
// 456.463 us; speedup vs baseline: 2.5272x; 1.0656x over previous
//
#include <hip/hip_runtime.h>

#define BB 32
#define NN 512
#define EE 256
#define HH 8
#define HDD 32

typedef __attribute__((ext_vector_type(4))) float f32x4;
typedef __attribute__((ext_vector_type(8))) short s16x8;
typedef unsigned short ushort_t;
typedef unsigned int uint_t;

__device__ __forceinline__ ushort_t f2bf(float f) {
  union { float f; uint_t u; } v; v.f = f;
  uint_t r = v.u + 0x7fffu + ((v.u >> 16) & 1u);
  return (ushort_t)(r >> 16);
}
__device__ __forceinline__ uint_t pk2(float a, float b) {
  return (uint_t)f2bf(a) | ((uint_t)f2bf(b) << 16);
}
__device__ __forceinline__ float bf2f(ushort_t u) {
  union { uint_t u; float f; } v; v.u = ((uint_t)u) << 16;
  return v.f;
}

// ---------------- Kernel 0: fp32 -> bf16 convert (x, in_w, out_w in one grid) ----------------
__global__ __launch_bounds__(256) void cvt_all(
    const float* __restrict__ x, const float* __restrict__ w1, const float* __restrict__ w2,
    ushort_t* __restrict__ xb, ushort_t* __restrict__ w1b, ushort_t* __restrict__ w2b) {
  const int NX = BB * NN * EE / 4;     // 1048576
  const int NW1 = 3 * EE * EE / 4;     // 49152
  const int NW2 = EE * EE / 4;         // 16384
  int i = blockIdx.x * 256 + threadIdx.x;
  const float* src; ushort_t* dst; int j;
  if (i < NX) { src = x; dst = xb; j = i; }
  else if (i < NX + NW1) { src = w1; dst = w1b; j = i - NX; }
  else if (i < NX + NW1 + NW2) { src = w2; dst = w2b; j = i - NX - NW1; }
  else return;
  float4 v = ((const float4*)src)[j];
  uint2 p; p.x = pk2(v.x, v.y); p.y = pk2(v.z, v.w);
  ((uint2*)dst)[j] = p;
}

// ---------------- Kernel 1: QKV projection (bf16 MFMA GEMM) ----------------
// 128x128 tile, 4 waves 2x2, BK=32. Q,K head-major [B,H,N,32]; V transposed [B,H,32,N].
__global__ __launch_bounds__(256) void qkv_mfma(
    const ushort_t* __restrict__ xb, const ushort_t* __restrict__ wb,
    const float* __restrict__ bias,
    ushort_t* __restrict__ Q, ushort_t* __restrict__ K, ushort_t* __restrict__ Vt) {
  __shared__ ushort_t sA[128][40];
  __shared__ ushort_t sB[128][40];
  int t = threadIdx.x;
  int bj = blockIdx.x % 6, bm = blockIdx.x / 6;
  int m0 = bm * 128, j0 = bj * 128;
  int w4 = t >> 6, lane = t & 63, quad = lane >> 4, l16 = lane & 15;
  int wy = w4 >> 1, wx = w4 & 1;
  f32x4 acc[4][4];
  #pragma unroll
  for (int a = 0; a < 4; a++)
    #pragma unroll
    for (int b = 0; b < 4; b++) acc[a][b] = (f32x4){0.f, 0.f, 0.f, 0.f};
  int sr2 = t >> 2, sc2 = (t & 3) * 8;
  for (int kk = 0; kk < 256; kk += 32) {
    __syncthreads();
    #pragma unroll
    for (int p = 0; p < 2; p++) {
      int r = sr2 + 64 * p;
      *(s16x8*)&sA[r][sc2] = *(const s16x8*)&xb[(size_t)(m0 + r) * 256 + kk + sc2];
      *(s16x8*)&sB[r][sc2] = *(const s16x8*)&wb[(size_t)(j0 + r) * 256 + kk + sc2];
    }
    __syncthreads();
    s16x8 af[4], bf[4];
    #pragma unroll
    for (int mt = 0; mt < 4; mt++)
      af[mt] = *(const s16x8*)&sA[wy * 64 + mt * 16 + l16][quad * 8];
    #pragma unroll
    for (int jt = 0; jt < 4; jt++)
      bf[jt] = *(const s16x8*)&sB[wx * 64 + jt * 16 + l16][quad * 8];
    #pragma unroll
    for (int mt = 0; mt < 4; mt++)
      #pragma unroll
      for (int jt = 0; jt < 4; jt++)
        acc[mt][jt] = __builtin_amdgcn_mfma_f32_16x16x32_bf16(af[mt], bf[jt], acc[mt][jt], 0, 0, 0);
  }
  #pragma unroll
  for (int jt = 0; jt < 4; jt++) {
    int j = j0 + wx * 64 + jt * 16 + l16;
    int which = j >> 8, e0 = j & 255, h = e0 >> 5, d0 = e0 & 31;
    float b = bias[j];
    #pragma unroll
    for (int mt = 0; mt < 4; mt++) {
      #pragma unroll
      for (int r = 0; r < 4; r++) {
        int m = m0 + wy * 64 + mt * 16 + quad * 4 + r;
        int bi = m >> 9, n = m & 511;
        ushort_t val = f2bf(acc[mt][jt][r] + b);
        if (which == 2) {
          Vt[((size_t)(bi * 8 + h) * 32 + d0) * 512 + n] = val;
        } else {
          ushort_t* dst = (which == 0) ? Q : K;
          dst[((size_t)(bi * 8 + h) * 512 + n) * 32 + d0] = val;
        }
      }
    }
  }
}

// ---------------- Kernel 2: fused attention + out-proj + mask + residual + LN ----------------
// block = (b, 16-q tile), 1024 blocks, 4 waves; wave w owns keys [w*128, w*128+128)
__global__ __launch_bounds__(256) void attn_fused(
    const ushort_t* __restrict__ Q, const ushort_t* __restrict__ K,
    const ushort_t* __restrict__ Vt, const int* __restrict__ pre_mask,
    const ushort_t* __restrict__ wob, const float* __restrict__ x,
    const float* __restrict__ out_b, const int* __restrict__ post_mask,
    const float* __restrict__ gamma, const float* __restrict__ beta,
    float* __restrict__ out, float* __restrict__ attnw) {
  __shared__ ushort_t sP[4][16 * 132];   // wave-private unnormalized e (bf16)
  __shared__ float sSum[2][4][16];       // double-buffered per-head row sums
  __shared__ float sO[4][16 * 33];       // per-wave PV partials
  __shared__ ushort_t sO16[16 * 260];    // assembled O tile (bf16, A-layout)
  __shared__ float sRed1[16][4];         // LN reduce
  __shared__ float sRed2[16][4];

  int t = threadIdx.x;
  int bb = blockIdx.x >> 5;
  int q0 = (blockIdx.x & 31) << 4;
  int w = t >> 6, lane = t & 63, quad = lane >> 4, l16 = lane & 15;
  int kbase = w * 128;
  const float scale = 0.17677669529663687f;  // 1/sqrt(32)
  ushort_t* mysP = &sP[w][0];

  float wmean[4][8];
  #pragma unroll
  for (int i = 0; i < 4; i++)
    #pragma unroll
    for (int j = 0; j < 8; j++) wmean[i][j] = 0.f;

  for (int h = 0; h < 8; h++) {
    size_t base = ((size_t)(bb * 8 + h) * 512) * 32;
    const int* mbase = pre_mask + ((size_t)(bb * 8 + h) * 512 + q0) * 512;

    // Q A-frag direct from global (no LDS stage, no barrier)
    s16x8 afrag = *(const s16x8*)&Q[base + (size_t)(q0 + l16) * 32 + quad * 8];

    // ---- scores + exp + wave-private sP + partial sums ----
    float psum[4] = {0.f, 0.f, 0.f, 0.f};
    #pragma unroll
    for (int t8 = 0; t8 < 8; t8++) {
      int n0 = kbase + t8 * 16;
      s16x8 bfrag = *(const s16x8*)&K[base + (size_t)(n0 + l16) * 32 + quad * 8];
      f32x4 acc = {0.f, 0.f, 0.f, 0.f};
      acc = __builtin_amdgcn_mfma_f32_16x16x32_bf16(afrag, bfrag, acc, 0, 0, 0);
      #pragma unroll
      for (int i = 0; i < 4; i++) {
        int msk = mbase[(quad * 4 + i) * 512 + n0 + l16];
        float e = msk ? 0.f : __expf(acc[i] * scale);
        mysP[(quad * 4 + i) * 132 + t8 * 16 + l16] = f2bf(e);
        psum[i] += e;
      }
    }
    #pragma unroll
    for (int i = 0; i < 4; i++) {
      float s = psum[i];
      s += __shfl_xor(s, 1, 64);
      s += __shfl_xor(s, 2, 64);
      s += __shfl_xor(s, 4, 64);
      s += __shfl_xor(s, 8, 64);
      psum[i] = s;
    }
    if (l16 == 0) {
      #pragma unroll
      for (int i = 0; i < 4; i++) sSum[h & 1][w][quad * 4 + i] = psum[i];
    }
    __syncthreads();   // B2: sSum ready (also fences prior head's epilogue reads of sO)

    // ---- head-mean weights: re-read own sP (frees ev registers) ----
    float inv[4];
    #pragma unroll
    for (int i = 0; i < 4; i++) {
      int r = quad * 4 + i;
      inv[i] = 0.125f / (sSum[h & 1][0][r] + sSum[h & 1][1][r] + sSum[h & 1][2][r] + sSum[h & 1][3][r]);
    }
    #pragma unroll
    for (int t8 = 0; t8 < 8; t8++)
      #pragma unroll
      for (int i = 0; i < 4; i++)
        wmean[i][t8] += inv[i] * bf2f(mysP[(quad * 4 + i) * 132 + t8 * 16 + l16]);

    // ---- PV over own 128-k slice (unnormalized); wave-private sP, no barrier ----
    f32x4 oacc[2];
    oacc[0] = (f32x4){0.f, 0.f, 0.f, 0.f};
    oacc[1] = (f32x4){0.f, 0.f, 0.f, 0.f};
    #pragma unroll
    for (int ks = 0; ks < 4; ks++) {
      s16x8 pa = *(const s16x8*)&mysP[l16 * 132 + ks * 32 + quad * 8];
      #pragma unroll
      for (int dt = 0; dt < 2; dt++) {
        s16x8 vb = *(const s16x8*)&Vt[base + (size_t)(dt * 16 + l16) * 512 + kbase + ks * 32 + quad * 8];
        oacc[dt] = __builtin_amdgcn_mfma_f32_16x16x32_bf16(pa, vb, oacc[dt], 0, 0, 0);
      }
    }
    #pragma unroll
    for (int dt = 0; dt < 2; dt++)
      #pragma unroll
      for (int i = 0; i < 4; i++)
        sO[w][(quad * 4 + i) * 33 + dt * 16 + l16] = oacc[dt][i];
    __syncthreads();   // B3: sO ready

    // ---- combine waves, normalize, stash O tile in LDS (bf16 A-layout) ----
    {
      int r = t >> 4;
      int c = (t & 15) * 2;
      float s0 = sO[0][r * 33 + c] + sO[1][r * 33 + c] + sO[2][r * 33 + c] + sO[3][r * 33 + c];
      float s1 = sO[0][r * 33 + c + 1] + sO[1][r * 33 + c + 1] + sO[2][r * 33 + c + 1] + sO[3][r * 33 + c + 1];
      float invr = 1.0f / (sSum[h & 1][0][r] + sSum[h & 1][1][r] + sSum[h & 1][2][r] + sSum[h & 1][3][r]);
      *(uint_t*)&sO16[r * 260 + h * 32 + c] = pk2(s0 * invr, s1 * invr);
    }
  }

  // ---- head-averaged attention weights ----
  {
    float* arow = attnw + (size_t)(bb * 512 + q0) * 512;
    #pragma unroll
    for (int i = 0; i < 4; i++)
      #pragma unroll
      for (int t8 = 0; t8 < 8; t8++)
        arow[(quad * 4 + i) * 512 + kbase + t8 * 16 + l16] = wmean[i][t8];
  }
  __syncthreads();   // Bf: sO16 complete

  // ---- fused out-proj: wave w owns cols [w*64, w*64+64) ----
  int jr0 = w * 64;
  f32x4 pacc[4];
  #pragma unroll
  for (int jt = 0; jt < 4; jt++) pacc[jt] = (f32x4){0.f, 0.f, 0.f, 0.f};
  #pragma unroll
  for (int kc = 0; kc < 8; kc++) {
    s16x8 pa = *(const s16x8*)&sO16[l16 * 260 + kc * 32 + quad * 8];
    #pragma unroll
    for (int jt = 0; jt < 4; jt++) {
      s16x8 bf = *(const s16x8*)&wob[(size_t)(jr0 + jt * 16 + l16) * 256 + kc * 32 + quad * 8];
      pacc[jt] = __builtin_amdgcn_mfma_f32_16x16x32_bf16(pa, bf, pacc[jt], 0, 0, 0);
    }
  }

  // ---- post-mask + residual + LayerNorm ----
  float g4[4], bt4[4], ob4[4];
  #pragma unroll
  for (int jt = 0; jt < 4; jt++) {
    int j = jr0 + jt * 16 + l16;
    g4[jt] = gamma[j]; bt4[jt] = beta[j]; ob4[jt] = out_b[j];
  }
  float yv[4][4];
  #pragma unroll
  for (int i = 0; i < 4; i++) {
    int r = quad * 4 + i;
    int m = bb * 512 + q0 + r;
    bool msk = post_mask[m] != 0;
    float s1 = 0.f, s2 = 0.f;
    #pragma unroll
    for (int jt = 0; jt < 4; jt++) {
      int j = jr0 + jt * 16 + l16;
      float p = msk ? 0.f : (pacc[jt][i] + ob4[jt]);
      float yy = x[(size_t)m * 256 + j] + p;
      yv[i][jt] = yy; s1 += yy; s2 += yy * yy;
    }
    s1 += __shfl_xor(s1, 1, 64); s1 += __shfl_xor(s1, 2, 64);
    s1 += __shfl_xor(s1, 4, 64); s1 += __shfl_xor(s1, 8, 64);
    s2 += __shfl_xor(s2, 1, 64); s2 += __shfl_xor(s2, 2, 64);
    s2 += __shfl_xor(s2, 4, 64); s2 += __shfl_xor(s2, 8, 64);
    if (l16 == 0) { sRed1[r][w] = s1; sRed2[r][w] = s2; }
  }
  __syncthreads();
  #pragma unroll
  for (int i = 0; i < 4; i++) {
    int r = quad * 4 + i;
    int m = bb * 512 + q0 + r;
    float S1 = sRed1[r][0] + sRed1[r][1] + sRed1[r][2] + sRed1[r][3];
    float S2 = sRed2[r][0] + sRed2[r][1] + sRed2[r][2] + sRed2[r][3];
    float mu = S1 * (1.0f / 256.0f);
    float var = S2 * (1.0f / 256.0f) - mu * mu;
    float rstd = rsqrtf(var + 1e-5f);
    #pragma unroll
    for (int jt = 0; jt < 4; jt++) {
      int j = jr0 + jt * 16 + l16;
      out[(size_t)m * 256 + j] = (yv[i][jt] - mu) * rstd * g4[jt] + bt4[jt];
    }
  }
}

extern "C" void kernel_launch(void* const* d_in, const int* in_sizes, int n_in,
                              void* d_out, int out_size, void* d_ws, size_t ws_size,
                              hipStream_t stream) {
  const float* x       = (const float*)d_in[0];
  const int*   pre_m   = (const int*)d_in[1];
  const int*   post_m  = (const int*)d_in[2];
  const float* in_w    = (const float*)d_in[3];
  const float* in_b    = (const float*)d_in[4];
  const float* out_w   = (const float*)d_in[5];
  const float* out_b   = (const float*)d_in[6];
  const float* gamma   = (const float*)d_in[7];
  const float* beta    = (const float*)d_in[8];
  float* out   = (float*)d_out;                       // [B,N,E]
  float* attnw = out + (size_t)BB * NN * EE;          // [B,N,N]
  ushort_t* Q   = (ushort_t*)d_ws;                    // bf16 [B,H,N,32]
  ushort_t* K   = Q  + (size_t)BB * HH * NN * HDD;    // bf16 [B,H,N,32]
  ushort_t* Vt  = K  + (size_t)BB * HH * NN * HDD;    // bf16 [B,H,32,N]
  ushort_t* xb  = Vt + (size_t)BB * HH * NN * HDD;    // bf16 [B*N, E]
  ushort_t* wib = xb + (size_t)BB * NN * EE;          // bf16 [768, 256]
  ushort_t* wob = wib + (size_t)3 * EE * EE;          // bf16 [256, 256]

  const int NCVT = BB * NN * EE / 4 + 3 * EE * EE / 4 + EE * EE / 4;
  cvt_all<<<dim3((NCVT + 255) / 256), dim3(256), 0, stream>>>(x, in_w, out_w, xb, wib, wob);
  qkv_mfma<<<dim3(768), dim3(256), 0, stream>>>(xb, wib, in_b, Q, K, Vt);
  attn_fused<<<dim3(1024), dim3(256), 0, stream>>>(Q, K, Vt, pre_m, wob, x, out_b, post_m,
                                                   gamma, beta, out, attnw);
}